// Round 3
// baseline (316.574 us; speedup 1.0000x reference)
//
#include <hip/hip_runtime.h>
#include <hip/hip_bf16.h>

#define B_DIM 4096
#define K_TOT 2048   // IN + H
#define H_DIM 1024

typedef short bf16x8 __attribute__((ext_vector_type(8)));
typedef float f32x4 __attribute__((ext_vector_type(4)));
typedef unsigned short u16x8 __attribute__((ext_vector_type(8)));

typedef __attribute__((address_space(1))) const unsigned gas_u32;
typedef __attribute__((address_space(3))) unsigned las_u32;

static __device__ __forceinline__ unsigned short f2bf(float f) {
  union { float f; unsigned u; } v; v.f = f;
  unsigned r = v.u + 0x7FFF + ((v.u >> 16) & 1);  // RNE
  return (unsigned short)(r >> 16);
}

// ---- one pack kernel: blocks [0,4096) pack A=[x|h], [4096,8192) pack W ----
__global__ void pack_all(const float* __restrict__ x, const float* __restrict__ hp,
                         const float* __restrict__ W0, const float* __restrict__ W1,
                         const float* __restrict__ W2, const float* __restrict__ W3,
                         const float* __restrict__ W4, const float* __restrict__ W5,
                         const float* __restrict__ W6, const float* __restrict__ W7,
                         u16x8* __restrict__ A, u16x8* __restrict__ Wc) {
  int blk = blockIdx.x;
  const float* src;
  u16x8* dst;
  int t;
  if (blk < 4096) {
    t = blk * blockDim.x + threadIdx.x;
    int idx = t << 3;
    int b = idx >> 11;
    int k = idx & 2047;
    src = (k < 1024) ? (x + b * 1024 + k) : (hp + b * 1024 + (k - 1024));
    dst = A + t;
  } else {
    t = (blk - 4096) * blockDim.x + threadIdx.x;
    int idx = t << 3;
    int n = idx >> 11;                // output row (gate*1024 + j)
    int k = idx & 2047;
    int gate = n >> 10;
    int j = n & 1023;
    int s = (k < 1024) ? gate : gate + 4;
    const float* base =
        (s == 0) ? W0 : (s == 1) ? W1 : (s == 2) ? W2 : (s == 3) ? W3 :
        (s == 4) ? W4 : (s == 5) ? W5 : (s == 6) ? W6 : W7;
    src = base + j * 1024 + (k & 1023);
    dst = Wc + t;
  }
  float4 lo = *(const float4*)src;
  float4 hi = *(const float4*)(src + 4);
  u16x8 v;
  v[0] = f2bf(lo.x); v[1] = f2bf(lo.y); v[2] = f2bf(lo.z); v[3] = f2bf(lo.w);
  v[4] = f2bf(hi.x); v[5] = f2bf(hi.y); v[6] = f2bf(hi.z); v[7] = f2bf(hi.w);
  *dst = v;
}

// ------------- fused GEMM + LSTM, small sync domains -------------
// Block: 2 waves, 64 rows x (4 gates x 32 j). Wave: 64 rows x (4 gates x 16 j).
// Grid 2048 blocks -> 8 blocks/CU, 8 independent barrier groups per CU.
// LDS slot swizzle g = s ^ ((r>>1)&3): ds_read_b128 conflict-free (R2: 0 conflicts).
static __device__ __forceinline__ float sigm(float x) {
  return 1.0f / (1.0f + __expf(-x));
}
static __device__ __forceinline__ float tanh_fast(float x) {
  x = fminf(fmaxf(x, -15.f), 15.f);
  float t = __expf(-2.0f * x);
  return (1.0f - t) / (1.0f + t);
}

__global__ __launch_bounds__(128) void gemm_lstm(
    const unsigned short* __restrict__ A,   // B x 2048 bf16
    const unsigned short* __restrict__ W,   // 4096 x 2048 bf16, gate-major rows
    const float* __restrict__ cp,
    const float* __restrict__ bii, const float* __restrict__ bif,
    const float* __restrict__ big, const float* __restrict__ bio,
    float* __restrict__ out) {
  __shared__ unsigned short As[64 * 32];    // 4 KB
  __shared__ unsigned short Bs[128 * 32];   // 8 KB
  const int tid = threadIdx.x;
  const int wave = tid >> 6;            // 0..1
  const int lane = tid & 63;
  const int m0 = blockIdx.y << 6;       // 64-row strip
  const int j0 = blockIdx.x << 5;       // 32-wide j strip
  const int wj16 = wave << 4;           // wave j half (16)

  f32x4 acc[4][4];
#pragma unroll
  for (int mi = 0; mi < 4; ++mi)
#pragma unroll
    for (int ni = 0; ni < 4; ++ni)
      acc[mi][ni] = (f32x4){0.f, 0.f, 0.f, 0.f};

  // ---- staging: wave stages A chunks {2w,2w+1}, B chunks {4w..4w+3}
  const int lr = lane >> 2;                       // row within 16-row chunk
  const int ls = lane & 3;                        // LDS 16B slot
  const int g  = ls ^ ((lr >> 1) & 3);            // swizzled global k-group

  const int ca = wave * 2;
  const unsigned short* aptr0 = A + (long)(m0 + ca * 16 + lr) * K_TOT + g * 8;
  const unsigned short* aptr1 = A + (long)(m0 + (ca + 1) * 16 + lr) * K_TOT + g * 8;
  char* lA0 = (char*)As + ca * 1024;
  char* lA1 = lA0 + 1024;

  const int cb = wave * 4;
  const unsigned short* bptr[4];
  char* lB[4];
#pragma unroll
  for (int q = 0; q < 4; ++q) {
    int rr = (cb + q) * 16 + lr;                  // LDS B row
    bptr[q] = W + (long)((rr >> 5) * 1024 + j0 + (rr & 31)) * K_TOT + g * 8;
    lB[q] = (char*)Bs + (cb + q) * 1024;
  }

  const int fr = lane & 15;                       // fragment row within 16-tile
  const int gg = lane >> 4;                       // k-group 0..3
  const int sl = (gg ^ ((fr >> 1) & 3)) * 16;     // swizzled slot byte offset

  for (int k0 = 0; k0 < K_TOT; k0 += 32) {
    __builtin_amdgcn_global_load_lds((gas_u32*)(aptr0 + k0), (las_u32*)lA0, 16, 0, 0);
    __builtin_amdgcn_global_load_lds((gas_u32*)(aptr1 + k0), (las_u32*)lA1, 16, 0, 0);
#pragma unroll
    for (int q = 0; q < 4; ++q)
      __builtin_amdgcn_global_load_lds((gas_u32*)(bptr[q] + k0), (las_u32*)lB[q], 16, 0, 0);
    __syncthreads();
    bf16x8 af[4], bfv[4];
#pragma unroll
    for (int i = 0; i < 4; ++i) {
      af[i]  = *(const bf16x8*)((const char*)As + (i * 16 + fr) * 64 + sl);
      bfv[i] = *(const bf16x8*)((const char*)Bs + (i * 32 + wj16 + fr) * 64 + sl);
    }
#pragma unroll
    for (int mi = 0; mi < 4; ++mi)
#pragma unroll
      for (int ni = 0; ni < 4; ++ni)
        acc[mi][ni] = __builtin_amdgcn_mfma_f32_16x16x32_bf16(af[mi], bfv[ni], acc[mi][ni], 0, 0, 0);
    __syncthreads();
  }

  // ---- fused LSTM epilogue
  // C/D layout: col=lane&15, row=(lane>>4)*4+reg  [m89/m91 verified]
  const int ccol = lane & 15;
  const int crow = (lane >> 4) * 4;
  const int j = j0 + wj16 + ccol;
  const float bi = bii[j];
  const float bff = bif[j];
  const float bg = big[j];
  const float bo = bio[j];
  const long BH = (long)B_DIM * H_DIM;
#pragma unroll
  for (int mi = 0; mi < 4; ++mi) {
#pragma unroll
    for (int reg = 0; reg < 4; ++reg) {
      const int row = m0 + mi * 16 + crow + reg;
      const long p = (long)row * H_DIM + j;
      const float cvp = cp[p];
      const float iv = sigm(acc[mi][0][reg] + bi);
      const float fv = sigm(acc[mi][1][reg] + bff);
      const float gv = tanh_fast(acc[mi][2][reg] + bg);
      const float ov = sigm(acc[mi][3][reg] + bo);
      const float cv = fv * cvp + iv * gv;
      const float hv = ov * tanh_fast(cv);
      out[p]          = hv;
      out[BH + p]     = cv;
      out[2 * BH + p] = iv;
      out[3 * BH + p] = fv;
      out[4 * BH + p] = gv;
      out[5 * BH + p] = ov;
    }
  }
}

extern "C" void kernel_launch(void* const* d_in, const int* in_sizes, int n_in,
                              void* d_out, int out_size, void* d_ws, size_t ws_size,
                              hipStream_t stream) {
  const float* x    = (const float*)d_in[0];
  const float* h    = (const float*)d_in[1];
  const float* c    = (const float*)d_in[2];
  const float* W_ii = (const float*)d_in[3];
  const float* b_ii = (const float*)d_in[4];
  const float* W_if = (const float*)d_in[5];
  const float* b_if = (const float*)d_in[6];
  const float* W_ig = (const float*)d_in[7];
  const float* b_ig = (const float*)d_in[8];
  const float* W_io = (const float*)d_in[9];
  const float* b_io = (const float*)d_in[10];
  const float* W_hi = (const float*)d_in[11];
  const float* W_hf = (const float*)d_in[12];
  const float* W_hg = (const float*)d_in[13];
  const float* W_ho = (const float*)d_in[14];

  // workspace: A_cat bf16 16MB | W_cat bf16 16MB
  unsigned short* Abf = (unsigned short*)d_ws;
  unsigned short* Wbf = (unsigned short*)((char*)d_ws + (size_t)16 * 1024 * 1024);

  pack_all<<<8192, 256, 0, stream>>>(x, h, W_ii, W_if, W_ig, W_io,
                                     W_hi, W_hf, W_hg, W_ho,
                                     (u16x8*)Abf, (u16x8*)Wbf);
  dim3 grid(H_DIM / 32, B_DIM / 64);   // 32 x 64 = 2048 blocks
  gemm_lstm<<<grid, 128, 0, stream>>>(Abf, Wbf, c, b_ii, b_if, b_ig, b_io,
                                      (float*)d_out);
}